// Round 2
// baseline (229.252 us; speedup 1.0000x reference)
//
#include <hip/hip_runtime.h>

// KeyValueMemoryNetwork: B=16, S=2048, C=16, D=256, V=100000
// One wave per token (b,s). Lane l owns D-elements [4l, 4l+4).
// R2: force all 16 gathered rows to stay resident in VGPRs (R1's VGPR=48
// showed the compiler rematerialized the gather loads and serialized them).
// Structure: issue all 16 loads back-to-back -> one wait -> compute.

#define KV_C 16
#define KV_D 256
#define KV_TOKENS (16 * 2048)

__global__ __launch_bounds__(256, 2) void kv_mem_kernel(
    const int* __restrict__ seq,      // [TOKENS, C] int32
    const float* __restrict__ hidden, // [TOKENS, D]
    const float* __restrict__ table,  // [V, D]
    float* __restrict__ out)          // [TOKENS, D]
{
    const int wave = threadIdx.x >> 6;
    const int lane = threadIdx.x & 63;
    const int token = blockIdx.x * 4 + wave;

    // hidden chunk for this lane
    const float4 h = *(const float4*)(hidden + (size_t)token * KV_D + lane * 4);

    // each of lanes 0..15 loads one index, broadcast via shuffle
    const int* sp = seq + (size_t)token * KV_C;
    int myidx = (lane < KV_C) ? sp[lane] : 0;

    float4 e[KV_C];

    // Phase 1: issue ALL 16 gather loads with no dependent compute between
    // them -> compiler emits 16 back-to-back global_load_dwordx4, max MLP.
    #pragma unroll
    for (int c = 0; c < KV_C; ++c) {
        int idx = __shfl(myidx, c);      // wave-uniform value
        float4 ev = make_float4(0.f, 0.f, 0.f, 0.f);
        if (idx != 0) {                   // padding_idx=0 -> zero row
            ev = *(const float4*)(table + (size_t)idx * KV_D + lane * 4);
        }
        e[c] = ev;
    }

    // Pin the fragments in registers: block rematerialization/reload of the
    // gather loads in the combine loop.
    #pragma unroll
    for (int c = 0; c < KV_C; ++c) {
        asm volatile("" : "+v"(e[c].x), "+v"(e[c].y), "+v"(e[c].z), "+v"(e[c].w));
    }

    // Phase 2: per-lane partial dot products
    float u[KV_C];
    #pragma unroll
    for (int c = 0; c < KV_C; ++c) {
        u[c] = h.x * e[c].x + h.y * e[c].y + h.z * e[c].z + h.w * e[c].w;
    }

    // butterfly reduce all 16 scores across the 64-lane wave
    #pragma unroll
    for (int s = 32; s >= 1; s >>= 1) {
        #pragma unroll
        for (int c = 0; c < KV_C; ++c) {
            u[c] += __shfl_xor(u[c], s);
        }
    }

    // softmax over C (wave-uniform, computed redundantly per lane)
    float m = u[0];
    #pragma unroll
    for (int c = 1; c < KV_C; ++c) m = fmaxf(m, u[c]);
    float sum = 0.f;
    #pragma unroll
    for (int c = 0; c < KV_C; ++c) {
        u[c] = __expf(u[c] - m);          // reuse u[] as p[]
        sum += u[c];
    }
    const float inv = 1.0f / sum;

    // weighted combine: o[d] = sum_c p[c] * e[c][d]
    float4 o = make_float4(0.f, 0.f, 0.f, 0.f);
    #pragma unroll
    for (int c = 0; c < KV_C; ++c) {
        const float w = u[c] * inv;
        o.x += w * e[c].x;
        o.y += w * e[c].y;
        o.z += w * e[c].z;
        o.w += w * e[c].w;
    }

    *(float4*)(out + (size_t)token * KV_D + lane * 4) = o;
}

extern "C" void kernel_launch(void* const* d_in, const int* in_sizes, int n_in,
                              void* d_out, int out_size, void* d_ws, size_t ws_size,
                              hipStream_t stream) {
    const int*   seq    = (const int*)d_in[0];
    const float* hidden = (const float*)d_in[1];
    const float* table  = (const float*)d_in[2];
    float*       out    = (float*)d_out;

    dim3 grid(KV_TOKENS / 4);   // 8192 blocks, 4 waves (tokens) per block
    dim3 block(256);
    kv_mem_kernel<<<grid, block, 0, stream>>>(seq, hidden, table, out);
}

// Round 3
// 228.338 us; speedup vs baseline: 1.0040x; 1.0040x over previous
//
#include <hip/hip_runtime.h>

// KeyValueMemoryNetwork: B=16, S=2048, C=16, D=256, V=100000
// One wave per token. Lane l owns D-elements [4l, 4l+4).
// R3: branchless gather (mask via __ballot) so all 16 global_load_dwordx4
// issue back-to-back; single-point asm pins (2 x 32 operands) force all 16
// rows resident -> no remat, max memory-level parallelism.

#define KV_C 16
#define KV_D 256
#define KV_TOKENS (16 * 2048)

__global__ __launch_bounds__(256, 2) void kv_mem_kernel(
    const int* __restrict__ seq,      // [TOKENS, C] int32
    const float* __restrict__ hidden, // [TOKENS, D]
    const float* __restrict__ table,  // [V, D]
    float* __restrict__ out)          // [TOKENS, D]
{
    const int wave = threadIdx.x >> 6;
    const int lane = threadIdx.x & 63;
    const int token = blockIdx.x * 4 + wave;

    // hidden chunk for this lane (issued first, consumed late)
    const float4 h = *(const float4*)(hidden + (size_t)token * KV_D + lane * 4);

    // lanes 0..15 load the 16 indices; broadcast via shuffle
    const int* sp = seq + (size_t)token * KV_C;
    int myidx = (lane < KV_C) ? sp[lane] : 0;

    // wave-uniform validity bitmask (bits 0..15)
    const unsigned long long nz = __ballot(myidx != 0);

    int idxs[KV_C];
    #pragma unroll
    for (int c = 0; c < KV_C; ++c) idxs[c] = __shfl(myidx, c);

    // Phase 1: 16 unconditional gathers, no control flow between them.
    float4 e[KV_C];
    #pragma unroll
    for (int c = 0; c < KV_C; ++c) {
        e[c] = *(const float4*)(table + (size_t)idxs[c] * KV_D + lane * 4);
    }

    // Single-point pins: all 16 loads must be issued before the first wait;
    // fragments become asm outputs -> cannot be rematerialized later.
    asm volatile("" :
        "+v"(e[0].x), "+v"(e[0].y), "+v"(e[0].z), "+v"(e[0].w),
        "+v"(e[1].x), "+v"(e[1].y), "+v"(e[1].z), "+v"(e[1].w),
        "+v"(e[2].x), "+v"(e[2].y), "+v"(e[2].z), "+v"(e[2].w),
        "+v"(e[3].x), "+v"(e[3].y), "+v"(e[3].z), "+v"(e[3].w),
        "+v"(e[4].x), "+v"(e[4].y), "+v"(e[4].z), "+v"(e[4].w),
        "+v"(e[5].x), "+v"(e[5].y), "+v"(e[5].z), "+v"(e[5].w),
        "+v"(e[6].x), "+v"(e[6].y), "+v"(e[6].z), "+v"(e[6].w),
        "+v"(e[7].x), "+v"(e[7].y), "+v"(e[7].z), "+v"(e[7].w));
    asm volatile("" :
        "+v"(e[8].x),  "+v"(e[8].y),  "+v"(e[8].z),  "+v"(e[8].w),
        "+v"(e[9].x),  "+v"(e[9].y),  "+v"(e[9].z),  "+v"(e[9].w),
        "+v"(e[10].x), "+v"(e[10].y), "+v"(e[10].z), "+v"(e[10].w),
        "+v"(e[11].x), "+v"(e[11].y), "+v"(e[11].z), "+v"(e[11].w),
        "+v"(e[12].x), "+v"(e[12].y), "+v"(e[12].z), "+v"(e[12].w),
        "+v"(e[13].x), "+v"(e[13].y), "+v"(e[13].z), "+v"(e[13].w),
        "+v"(e[14].x), "+v"(e[14].y), "+v"(e[14].z), "+v"(e[14].w),
        "+v"(e[15].x), "+v"(e[15].y), "+v"(e[15].z), "+v"(e[15].w));

    // Zero the padding rows (idx==0). Wave-uniform predicate -> cndmask/skip.
    #pragma unroll
    for (int c = 0; c < KV_C; ++c) {
        const float msk = ((nz >> c) & 1ULL) ? 1.0f : 0.0f;
        e[c].x *= msk; e[c].y *= msk; e[c].z *= msk; e[c].w *= msk;
    }

    // per-lane partial dot products
    float u[KV_C];
    #pragma unroll
    for (int c = 0; c < KV_C; ++c) {
        u[c] = h.x * e[c].x + h.y * e[c].y + h.z * e[c].z + h.w * e[c].w;
    }

    // butterfly reduce all 16 scores across the 64-lane wave
    #pragma unroll
    for (int s = 32; s >= 1; s >>= 1) {
        #pragma unroll
        for (int c = 0; c < KV_C; ++c) {
            u[c] += __shfl_xor(u[c], s);
        }
    }

    // softmax over C (wave-uniform, computed redundantly per lane)
    float m = u[0];
    #pragma unroll
    for (int c = 1; c < KV_C; ++c) m = fmaxf(m, u[c]);
    float sum = 0.f;
    #pragma unroll
    for (int c = 0; c < KV_C; ++c) {
        u[c] = __expf(u[c] - m);          // reuse u[] as p[]
        sum += u[c];
    }
    const float inv = 1.0f / sum;

    // weighted combine: o[d] = sum_c p[c] * e[c][d]
    float4 o = make_float4(0.f, 0.f, 0.f, 0.f);
    #pragma unroll
    for (int c = 0; c < KV_C; ++c) {
        const float w = u[c] * inv;
        o.x += w * e[c].x;
        o.y += w * e[c].y;
        o.z += w * e[c].z;
        o.w += w * e[c].w;
    }

    *(float4*)(out + (size_t)token * KV_D + lane * 4) = o;
}

extern "C" void kernel_launch(void* const* d_in, const int* in_sizes, int n_in,
                              void* d_out, int out_size, void* d_ws, size_t ws_size,
                              hipStream_t stream) {
    const int*   seq    = (const int*)d_in[0];
    const float* hidden = (const float*)d_in[1];
    const float* table  = (const float*)d_in[2];
    float*       out    = (float*)d_out;

    dim3 grid(KV_TOKENS / 4);   // 8192 blocks, 4 waves (tokens) per block
    dim3 block(256);
    kv_mem_kernel<<<grid, block, 0, stream>>>(seq, hidden, table, out);
}